// Round 1
// baseline (1149.081 us; speedup 1.0000x reference)
//
#include <hip/hip_runtime.h>
#include <math.h>

#define OBS 256
#define ACTD 64
#define NB 8192
#define NT 22
#define NSTEP 15
// M = NB*15 = 122880 rows for the gi GEMM

// ---------------------------------------------------------------------------
// Kernel 1: gi[b,t,j] = bias_ih[j] + sum_k x[b,t,k] * W_ih[j,k]
// x = concat(obs[b,t,:256], act[b,t,:64]); one thread per (b,t) row,
// 96 accumulators in VGPRs, W_ih read wave-uniformly (scalar loads).
// ---------------------------------------------------------------------------
__global__ __launch_bounds__(128) void k1_gi(
    const float* __restrict__ obs, const float* __restrict__ act,
    const float* __restrict__ Wih, const float* __restrict__ bih,
    float* __restrict__ gi)
{
    int g = blockIdx.x * 128 + threadIdx.x;   // exact grid: 0..122879
    int b = g / 15;
    int t = g - b * 15;
    const float* xo = obs + (size_t)(b * NT + t) * OBS;
    const float* xa = act + (size_t)(b * NT + t) * ACTD;

    float acc[96];
#pragma unroll
    for (int j = 0; j < 96; ++j) acc[j] = bih[j];

    // obs part: k = 0..255
#pragma unroll 1
    for (int kb = 0; kb < 256; kb += 16) {
        float xv[16];
        float4 a0 = *(const float4*)(xo + kb + 0);
        float4 a1 = *(const float4*)(xo + kb + 4);
        float4 a2 = *(const float4*)(xo + kb + 8);
        float4 a3 = *(const float4*)(xo + kb + 12);
        xv[0]=a0.x; xv[1]=a0.y; xv[2]=a0.z; xv[3]=a0.w;
        xv[4]=a1.x; xv[5]=a1.y; xv[6]=a1.z; xv[7]=a1.w;
        xv[8]=a2.x; xv[9]=a2.y; xv[10]=a2.z; xv[11]=a2.w;
        xv[12]=a3.x; xv[13]=a3.y; xv[14]=a3.z; xv[15]=a3.w;
#pragma unroll
        for (int j = 0; j < 96; ++j) {
            const float* w = Wih + j * 320 + kb;
#pragma unroll
            for (int kk = 0; kk < 16; ++kk)
                acc[j] = fmaf(w[kk], xv[kk], acc[j]);
        }
    }
    // act part: k = 256..319
#pragma unroll 1
    for (int kb = 0; kb < 64; kb += 16) {
        float xv[16];
        float4 a0 = *(const float4*)(xa + kb + 0);
        float4 a1 = *(const float4*)(xa + kb + 4);
        float4 a2 = *(const float4*)(xa + kb + 8);
        float4 a3 = *(const float4*)(xa + kb + 12);
        xv[0]=a0.x; xv[1]=a0.y; xv[2]=a0.z; xv[3]=a0.w;
        xv[4]=a1.x; xv[5]=a1.y; xv[6]=a1.z; xv[7]=a1.w;
        xv[8]=a2.x; xv[9]=a2.y; xv[10]=a2.z; xv[11]=a2.w;
        xv[12]=a3.x; xv[13]=a3.y; xv[14]=a3.z; xv[15]=a3.w;
#pragma unroll
        for (int j = 0; j < 96; ++j) {
            const float* w = Wih + j * 320 + 256 + kb;
#pragma unroll
            for (int kk = 0; kk < 16; ++kk)
                acc[j] = fmaf(w[kk], xv[kk], acc[j]);
        }
    }

    float4* o = (float4*)(gi + (size_t)g * 96);
#pragma unroll
    for (int j = 0; j < 24; ++j)
        o[j] = make_float4(acc[4*j], acc[4*j+1], acc[4*j+2], acc[4*j+3]);
}

// ---------------------------------------------------------------------------
// Kernel 2: per-row GRU recurrence + features + layernorm + MLP + argmax.
// One wave (64 threads) per batch row. Lanes mirror mod 32 for the gates.
// ---------------------------------------------------------------------------
__global__ __launch_bounds__(64) void k2_head(
    const float* __restrict__ obs, const float* __restrict__ act,
    const float* __restrict__ Whh, const float* __restrict__ bhh,
    const float* __restrict__ lng, const float* __restrict__ lnb,
    const float* __restrict__ W1, const float* __restrict__ b1,
    const float* __restrict__ W2, const float* __restrict__ b2,
    const float* __restrict__ W3, const float* __restrict__ b3,
    const float* __restrict__ gi,
    float* __restrict__ out_wl, float* __restrict__ out_mask)
{
    int b = blockIdx.x;
    int l = threadIdx.x;        // 0..63
    int jj = l & 31;            // gate row index (lanes 32..63 mirror 0..31)

    // preload W_hh rows jj, 32+jj, 64+jj and hidden biases
    float wr[32], wz[32], wn[32];
#pragma unroll
    for (int k = 0; k < 32; ++k) {
        wr[k] = Whh[(0  + jj) * 32 + k];
        wz[k] = Whh[(32 + jj) * 32 + k];
        wn[k] = Whh[(64 + jj) * 32 + k];
    }
    float br = bhh[jj], bz = bhh[32 + jj], bn = bhh[64 + jj];

    float hfull[32];
#pragma unroll
    for (int k = 0; k < 32; ++k) hfull[k] = 0.0f;
    float hown = 0.0f;

    const float* gib = gi + (size_t)b * NSTEP * 96;
    for (int t = 0; t < NSTEP; ++t) {
        float gi_r = gib[t * 96 + jj];
        float gi_z = gib[t * 96 + 32 + jj];
        float gi_n = gib[t * 96 + 64 + jj];
        float ar = br, az = bz, an = bn;
#pragma unroll
        for (int k = 0; k < 32; ++k) {
            ar = fmaf(wr[k], hfull[k], ar);
            az = fmaf(wz[k], hfull[k], az);
            an = fmaf(wn[k], hfull[k], an);
        }
        float r = 1.0f / (1.0f + expf(-(gi_r + ar)));
        float z = 1.0f / (1.0f + expf(-(gi_z + az)));
        float n = tanhf(gi_n + r * an);
        hown = (1.0f - z) * n + z * hown;
#pragma unroll
        for (int k = 0; k < 32; ++k) hfull[k] = __shfl(hown, k, 64);
    }
    // hfull now = h_n (identical on all 64 lanes)

    // ---- features ----
    float o14v[4], o13v[4], o12v[4], o11v[4];
#pragma unroll
    for (int q = 0; q < 4; ++q) {
        int i = l + 64 * q;
        o14v[q] = obs[(size_t)(b * NT + 14) * OBS + i];
        o13v[q] = obs[(size_t)(b * NT + 13) * OBS + i];
        o12v[q] = obs[(size_t)(b * NT + 12) * OBS + i];
        o11v[q] = obs[(size_t)(b * NT + 11) * OBS + i];
    }
    float ap = act[(size_t)(b * NT + 13) * ACTD + l];   // act_prev

    // softmax entropy over obs_t (row 14)
    float m = fmaxf(fmaxf(o14v[0], o14v[1]), fmaxf(o14v[2], o14v[3]));
#pragma unroll
    for (int o = 32; o >= 1; o >>= 1) m = fmaxf(m, __shfl_xor(m, o, 64));
    float e[4];
    float S = 0.0f, so = 0.0f;
#pragma unroll
    for (int q = 0; q < 4; ++q) {
        e[q] = expf(o14v[q] - m);
        S += e[q];
        so += o14v[q];
    }
#pragma unroll
    for (int o = 32; o >= 1; o >>= 1) { S += __shfl_xor(S, o, 64); so += __shfl_xor(so, o, 64); }
    float ent = 0.0f;
#pragma unroll
    for (int q = 0; q < 4; ++q) {
        float p = e[q] / S;
        ent += p * logf(p + 1e-8f);
    }
#pragma unroll
    for (int o = 32; o >= 1; o >>= 1) ent += __shfl_xor(ent, o, 64);
    ent = -ent;

    // rate of change
    float d1 = 0.0f, d2 = 0.0f, d3 = 0.0f;
#pragma unroll
    for (int q = 0; q < 4; ++q) {
        float a = o12v[q] - o11v[q]; d1 = fmaf(a, a, d1);
        a = o13v[q] - o12v[q];       d2 = fmaf(a, a, d2);
        a = o14v[q] - o13v[q];       d3 = fmaf(a, a, d3);
    }
#pragma unroll
    for (int o = 32; o >= 1; o >>= 1) {
        d1 += __shfl_xor(d1, o, 64); d2 += __shfl_xor(d2, o, 64); d3 += __shfl_xor(d3, o, 64);
    }
    float roc = (sqrtf(d1) + sqrtf(d2) + sqrtf(d3)) / 3.0f;

    // correlation
    float sa = ap;
#pragma unroll
    for (int o = 32; o >= 1; o >>= 1) sa += __shfl_xor(sa, o, 64);
    float mu_o = so / 256.0f;
    float mu_a = sa / 256.0f;
    float s_oa = 0.0f, s_oo = 0.0f, s_aa = 0.0f;
#pragma unroll
    for (int q = 0; q < 4; ++q) {
        float ov = o14v[q] - mu_o;
        float av = ((q == 0) ? ap : 0.0f) - mu_a;
        s_oa = fmaf(ov, av, s_oa);
        s_oo = fmaf(ov, ov, s_oo);
        s_aa = fmaf(av, av, s_aa);
    }
#pragma unroll
    for (int o = 32; o >= 1; o >>= 1) {
        s_oa += __shfl_xor(s_oa, o, 64); s_oo += __shfl_xor(s_oo, o, 64); s_aa += __shfl_xor(s_aa, o, 64);
    }
    float corr = s_oa / (sqrtf(s_oo) * sqrtf(s_aa) + 1e-8f);

    // ---- layernorm over feats[35] = [ent, roc, corr, h(32)] ----
    float fsum = ent + roc + corr;
#pragma unroll
    for (int k = 0; k < 32; ++k) fsum += hfull[k];
    float mu = fsum / 35.0f;
    float vs = (ent - mu) * (ent - mu) + (roc - mu) * (roc - mu) + (corr - mu) * (corr - mu);
#pragma unroll
    for (int k = 0; k < 32; ++k) { float dd = hfull[k] - mu; vs = fmaf(dd, dd, vs); }
    float sv = sqrtf(vs / 35.0f + 1e-5f);

    float fn[35];
    fn[0] = (ent - mu) / sv * lng[0] + lnb[0];
    fn[1] = (roc - mu) / sv * lng[1] + lnb[1];
    fn[2] = (corr - mu) / sv * lng[2] + lnb[2];
#pragma unroll
    for (int k = 0; k < 32; ++k)
        fn[3 + k] = (hfull[k] - mu) / sv * lng[3 + k] + lnb[3 + k];

    // ---- MLP ----
    float x1 = b1[l];
#pragma unroll
    for (int k = 0; k < 35; ++k) x1 = fmaf(W1[l * 35 + k], fn[k], x1);
    x1 = fmaxf(x1, 0.0f);
    float xf1[64];
#pragma unroll
    for (int k = 0; k < 64; ++k) xf1[k] = __shfl(x1, k, 64);

    float x2 = b2[jj];
#pragma unroll
    for (int k = 0; k < 64; ++k) x2 = fmaf(W2[jj * 64 + k], xf1[k], x2);
    x2 = fmaxf(x2, 0.0f);
    float xf2[32];
#pragma unroll
    for (int k = 0; k < 32; ++k) xf2[k] = __shfl(x2, k, 64);

    int lr = (l < 14) ? l : 0;
    float lg = b3[lr];
#pragma unroll
    for (int k = 0; k < 32; ++k) lg = fmaf(W3[lr * 32 + k], xf2[k], lg);

    // argmax over 14 logits (first max wins), redundantly on all lanes
    float best = -3.402823466e38f;
    int bi = 0;
#pragma unroll
    for (int j = 0; j < 14; ++j) {
        float v = __shfl(lg, j, 64);
        if (v > best) { best = v; bi = j; }
    }
    int wl = bi + 2;
    if (l == 0) out_wl[b] = (float)wl;
    int s  = (wl - 1) >> 1;
    int ee = wl >> 1;
    if (l < 15) {
        int off = l - 7;
        out_mask[b * 15 + l] = (off >= -s && off <= ee) ? 1.0f : 0.0f;
    }
}

// ---------------------------------------------------------------------------
// Kernel 3: padded_window = concat(obs[:,7:22], act[:,7:22]) * mask
// Pure bandwidth, float4 per thread. Exact grid: 8192*15*80 = 9,830,400.
// ---------------------------------------------------------------------------
__global__ __launch_bounds__(256) void k3_window(
    const float* __restrict__ obs, const float* __restrict__ act,
    const float* __restrict__ mask, float* __restrict__ out_pad)
{
    int idx = blockIdx.x * 256 + threadIdx.x;     // < 9830400
    int bt = idx / 80;
    int k4 = idx - bt * 80;
    int b = bt / 15;
    int t = bt - b * 15;
    float mval = mask[bt];
    float4 v;
    if (k4 < 64) {
        v = *(const float4*)(obs + (size_t)(b * NT + 7 + t) * OBS + k4 * 4);
    } else {
        v = *(const float4*)(act + (size_t)(b * NT + 7 + t) * ACTD + (k4 - 64) * 4);
    }
    v.x *= mval; v.y *= mval; v.z *= mval; v.w *= mval;
    ((float4*)out_pad)[idx] = v;
}

extern "C" void kernel_launch(void* const* d_in, const int* in_sizes, int n_in,
                              void* d_out, int out_size, void* d_ws, size_t ws_size,
                              hipStream_t stream) {
    const float* obs = (const float*)d_in[0];
    const float* act = (const float*)d_in[1];
    const float* Wih = (const float*)d_in[2];
    const float* Whh = (const float*)d_in[3];
    const float* bih = (const float*)d_in[4];
    const float* bhh = (const float*)d_in[5];
    const float* lng = (const float*)d_in[6];
    const float* lnb = (const float*)d_in[7];
    const float* W1  = (const float*)d_in[8];
    const float* b1  = (const float*)d_in[9];
    const float* W2  = (const float*)d_in[10];
    const float* b2  = (const float*)d_in[11];
    const float* W3  = (const float*)d_in[12];
    const float* b3  = (const float*)d_in[13];

    float* out      = (float*)d_out;
    float* out_wl   = out;                      // 8192
    float* out_pad  = out + NB;                 // 39,321,600
    float* out_mask = out + NB + NB * 15 * 320; // 122,880

    // Stage gi (122880*96 floats = 11.8M) inside the padded_window region;
    // it is consumed by k2 before k3 overwrites it.
    float* gi = out_pad;

    k1_gi<<<960, 128, 0, stream>>>(obs, act, Wih, bih, gi);
    k2_head<<<NB, 64, 0, stream>>>(obs, act, Whh, bhh, lng, lnb,
                                   W1, b1, W2, b2, W3, b3,
                                   gi, out_wl, out_mask);
    k3_window<<<38400, 256, 0, stream>>>(obs, act, out_mask, out_pad);
}

// Round 2
// 697.159 us; speedup vs baseline: 1.6482x; 1.6482x over previous
//
#include <hip/hip_runtime.h>
#include <math.h>

#define OBS 256
#define ACTD 64
#define NB 8192
#define NT 22
#define NSTEP 15

// ---------------------------------------------------------------------------
// Kernel 1: gi[b,t,j] = bias_ih[j] + sum_k x[b,t,k] * W_ih[j,k]
// Gate-split: blockIdx.y = gate block (32 rows of W_ih each).
// One thread per (b,t) row, 32 accumulators in VGPRs (no spill),
// W_ih addresses wave-uniform -> scalar loads on the SMEM pipe.
// ---------------------------------------------------------------------------
__global__ __launch_bounds__(128) void k1_gi(
    const float* __restrict__ obs, const float* __restrict__ act,
    const float* __restrict__ Wih, const float* __restrict__ bih,
    float* __restrict__ gi)
{
    int g = blockIdx.x * 128 + threadIdx.x;   // row id 0..122879
    int gate = blockIdx.y;                    // 0..2 (wave-uniform)
    int b = g / 15;
    int t = g - b * 15;
    const float* xo = obs + (size_t)(b * NT + t) * OBS;
    const float* xa = act + (size_t)(b * NT + t) * ACTD;
    const float* Wg = Wih + (size_t)gate * 32 * 320;
    const float* bg = bih + gate * 32;

    float acc[32];
#pragma unroll
    for (int j = 0; j < 32; ++j) acc[j] = bg[j];

    // obs part: k = 0..255
#pragma unroll 1
    for (int kb = 0; kb < 256; kb += 8) {
        float xv[8];
        float4 a0 = *(const float4*)(xo + kb + 0);
        float4 a1 = *(const float4*)(xo + kb + 4);
        xv[0]=a0.x; xv[1]=a0.y; xv[2]=a0.z; xv[3]=a0.w;
        xv[4]=a1.x; xv[5]=a1.y; xv[6]=a1.z; xv[7]=a1.w;
#pragma unroll
        for (int j = 0; j < 32; ++j) {
            const float* w = Wg + j * 320 + kb;
#pragma unroll
            for (int kk = 0; kk < 8; ++kk)
                acc[j] = fmaf(w[kk], xv[kk], acc[j]);
        }
    }
    // act part: k = 256..319
#pragma unroll 1
    for (int kb = 0; kb < 64; kb += 8) {
        float xv[8];
        float4 a0 = *(const float4*)(xa + kb + 0);
        float4 a1 = *(const float4*)(xa + kb + 4);
        xv[0]=a0.x; xv[1]=a0.y; xv[2]=a0.z; xv[3]=a0.w;
        xv[4]=a1.x; xv[5]=a1.y; xv[6]=a1.z; xv[7]=a1.w;
#pragma unroll
        for (int j = 0; j < 32; ++j) {
            const float* w = Wg + j * 320 + 256 + kb;
#pragma unroll
            for (int kk = 0; kk < 8; ++kk)
                acc[j] = fmaf(w[kk], xv[kk], acc[j]);
        }
    }

    float4* o = (float4*)(gi + (size_t)g * 96 + gate * 32);
#pragma unroll
    for (int j = 0; j < 8; ++j)
        o[j] = make_float4(acc[4*j], acc[4*j+1], acc[4*j+2], acc[4*j+3]);
}

// ---------------------------------------------------------------------------
// Kernel 2: per-row GRU recurrence + features + layernorm + MLP + argmax.
// One wave (64 threads) per batch row. Lanes mirror mod 32 for the gates.
// No big scratch arrays in the epilogue: shfl values consumed immediately,
// layernorm fused into the W1 dot.
// ---------------------------------------------------------------------------
__global__ __launch_bounds__(64) void k2_head(
    const float* __restrict__ obs, const float* __restrict__ act,
    const float* __restrict__ Whh, const float* __restrict__ bhh,
    const float* __restrict__ lng, const float* __restrict__ lnb,
    const float* __restrict__ W1, const float* __restrict__ b1,
    const float* __restrict__ W2, const float* __restrict__ b2,
    const float* __restrict__ W3, const float* __restrict__ b3,
    const float* __restrict__ gi,
    float* __restrict__ out_wl, float* __restrict__ out_mask)
{
    int b = blockIdx.x;
    int l = threadIdx.x;        // 0..63
    int jj = l & 31;            // gate row index (lanes 32..63 mirror 0..31)

    // preload W_hh rows jj, 32+jj, 64+jj and hidden biases
    float wr[32], wz[32], wn[32];
#pragma unroll
    for (int k = 0; k < 32; ++k) {
        wr[k] = Whh[(0  + jj) * 32 + k];
        wz[k] = Whh[(32 + jj) * 32 + k];
        wn[k] = Whh[(64 + jj) * 32 + k];
    }
    float br = bhh[jj], bz = bhh[32 + jj], bn = bhh[64 + jj];

    float hfull[32];
#pragma unroll
    for (int k = 0; k < 32; ++k) hfull[k] = 0.0f;
    float hown = 0.0f;

    const float* gib = gi + (size_t)b * NSTEP * 96;
    for (int t = 0; t < NSTEP; ++t) {
        float gi_r = gib[t * 96 + jj];
        float gi_z = gib[t * 96 + 32 + jj];
        float gi_n = gib[t * 96 + 64 + jj];
        float ar = br, az = bz, an = bn;
#pragma unroll
        for (int k = 0; k < 32; ++k) {
            ar = fmaf(wr[k], hfull[k], ar);
            az = fmaf(wz[k], hfull[k], az);
            an = fmaf(wn[k], hfull[k], an);
        }
        float r = 1.0f / (1.0f + expf(-(gi_r + ar)));
        float z = 1.0f / (1.0f + expf(-(gi_z + az)));
        float n = tanhf(gi_n + r * an);
        hown = (1.0f - z) * n + z * hown;
#pragma unroll
        for (int k = 0; k < 32; ++k) hfull[k] = __shfl(hown, k, 64);
    }
    // hfull now = h_n (identical on all 64 lanes)

    // ---- features ----
    float o14v[4], o13v[4], o12v[4], o11v[4];
#pragma unroll
    for (int q = 0; q < 4; ++q) {
        int i = l + 64 * q;
        o14v[q] = obs[(size_t)(b * NT + 14) * OBS + i];
        o13v[q] = obs[(size_t)(b * NT + 13) * OBS + i];
        o12v[q] = obs[(size_t)(b * NT + 12) * OBS + i];
        o11v[q] = obs[(size_t)(b * NT + 11) * OBS + i];
    }
    float ap = act[(size_t)(b * NT + 13) * ACTD + l];   // act_prev

    // softmax entropy over obs_t (row 14)
    float m = fmaxf(fmaxf(o14v[0], o14v[1]), fmaxf(o14v[2], o14v[3]));
#pragma unroll
    for (int o = 32; o >= 1; o >>= 1) m = fmaxf(m, __shfl_xor(m, o, 64));
    float e[4];
    float S = 0.0f, so = 0.0f;
#pragma unroll
    for (int q = 0; q < 4; ++q) {
        e[q] = expf(o14v[q] - m);
        S += e[q];
        so += o14v[q];
    }
#pragma unroll
    for (int o = 32; o >= 1; o >>= 1) { S += __shfl_xor(S, o, 64); so += __shfl_xor(so, o, 64); }
    float ent = 0.0f;
#pragma unroll
    for (int q = 0; q < 4; ++q) {
        float p = e[q] / S;
        ent += p * logf(p + 1e-8f);
    }
#pragma unroll
    for (int o = 32; o >= 1; o >>= 1) ent += __shfl_xor(ent, o, 64);
    ent = -ent;

    // rate of change
    float d1 = 0.0f, d2 = 0.0f, d3 = 0.0f;
#pragma unroll
    for (int q = 0; q < 4; ++q) {
        float a = o12v[q] - o11v[q]; d1 = fmaf(a, a, d1);
        a = o13v[q] - o12v[q];       d2 = fmaf(a, a, d2);
        a = o14v[q] - o13v[q];       d3 = fmaf(a, a, d3);
    }
#pragma unroll
    for (int o = 32; o >= 1; o >>= 1) {
        d1 += __shfl_xor(d1, o, 64); d2 += __shfl_xor(d2, o, 64); d3 += __shfl_xor(d3, o, 64);
    }
    float roc = (sqrtf(d1) + sqrtf(d2) + sqrtf(d3)) / 3.0f;

    // correlation
    float sa = ap;
#pragma unroll
    for (int o = 32; o >= 1; o >>= 1) sa += __shfl_xor(sa, o, 64);
    float mu_o = so / 256.0f;
    float mu_a = sa / 256.0f;
    float s_oa = 0.0f, s_oo = 0.0f, s_aa = 0.0f;
#pragma unroll
    for (int q = 0; q < 4; ++q) {
        float ov = o14v[q] - mu_o;
        float av = ((q == 0) ? ap : 0.0f) - mu_a;
        s_oa = fmaf(ov, av, s_oa);
        s_oo = fmaf(ov, ov, s_oo);
        s_aa = fmaf(av, av, s_aa);
    }
#pragma unroll
    for (int o = 32; o >= 1; o >>= 1) {
        s_oa += __shfl_xor(s_oa, o, 64); s_oo += __shfl_xor(s_oo, o, 64); s_aa += __shfl_xor(s_aa, o, 64);
    }
    float corr = s_oa / (sqrtf(s_oo) * sqrtf(s_aa) + 1e-8f);

    // ---- layernorm stats over feats[35] = [ent, roc, corr, h(32)] ----
    float fsum = ent + roc + corr;
#pragma unroll
    for (int k = 0; k < 32; ++k) fsum += hfull[k];
    float mu = fsum / 35.0f;
    float vs = (ent - mu) * (ent - mu) + (roc - mu) * (roc - mu) + (corr - mu) * (corr - mu);
#pragma unroll
    for (int k = 0; k < 32; ++k) { float dd = hfull[k] - mu; vs = fmaf(dd, dd, vs); }
    float inv_sv = rsqrtf(vs / 35.0f + 1e-5f);
    // use 1/sqrt via sqrt to match precision closely
    inv_sv = 1.0f / sqrtf(vs / 35.0f + 1e-5f);

    // ---- MLP: layernorm fused into W1 dot, no scratch arrays ----
    float x1 = b1[l];
#pragma unroll
    for (int k = 0; k < 35; ++k) {
        float f = (k == 0) ? ent : (k == 1) ? roc : (k == 2) ? corr : hfull[k - 3];
        float fnk = (f - mu) * inv_sv * lng[k] + lnb[k];
        x1 = fmaf(W1[l * 35 + k], fnk, x1);
    }
    x1 = fmaxf(x1, 0.0f);

    float x2 = b2[jj];
#pragma unroll
    for (int k = 0; k < 64; ++k)
        x2 = fmaf(W2[jj * 64 + k], __shfl(x1, k, 64), x2);
    x2 = fmaxf(x2, 0.0f);

    int lr = (l < 14) ? l : 0;
    float lg = b3[lr];
#pragma unroll
    for (int k = 0; k < 32; ++k)
        lg = fmaf(W3[lr * 32 + k], __shfl(x2, k, 64), lg);

    // argmax over 14 logits (first max wins), redundantly on all lanes
    float best = -3.402823466e38f;
    int bi = 0;
#pragma unroll
    for (int j = 0; j < 14; ++j) {
        float v = __shfl(lg, j, 64);
        if (v > best) { best = v; bi = j; }
    }
    int wl = bi + 2;
    if (l == 0) out_wl[b] = (float)wl;
    int s  = (wl - 1) >> 1;
    int ee = wl >> 1;
    if (l < 15) {
        int off = l - 7;
        out_mask[b * 15 + l] = (off >= -s && off <= ee) ? 1.0f : 0.0f;
    }
}

// ---------------------------------------------------------------------------
// Kernel 3: padded_window = concat(obs[:,7:22], act[:,7:22]) * mask
// Pure bandwidth, float4 per thread. Exact grid: 8192*15*80 = 9,830,400.
// ---------------------------------------------------------------------------
__global__ __launch_bounds__(256) void k3_window(
    const float* __restrict__ obs, const float* __restrict__ act,
    const float* __restrict__ mask, float* __restrict__ out_pad)
{
    int idx = blockIdx.x * 256 + threadIdx.x;     // < 9830400
    int bt = idx / 80;
    int k4 = idx - bt * 80;
    int b = bt / 15;
    int t = bt - b * 15;
    float mval = mask[bt];
    float4 v;
    if (k4 < 64) {
        v = *(const float4*)(obs + (size_t)(b * NT + 7 + t) * OBS + k4 * 4);
    } else {
        v = *(const float4*)(act + (size_t)(b * NT + 7 + t) * ACTD + (k4 - 64) * 4);
    }
    v.x *= mval; v.y *= mval; v.z *= mval; v.w *= mval;
    ((float4*)out_pad)[idx] = v;
}

extern "C" void kernel_launch(void* const* d_in, const int* in_sizes, int n_in,
                              void* d_out, int out_size, void* d_ws, size_t ws_size,
                              hipStream_t stream) {
    const float* obs = (const float*)d_in[0];
    const float* act = (const float*)d_in[1];
    const float* Wih = (const float*)d_in[2];
    const float* Whh = (const float*)d_in[3];
    const float* bih = (const float*)d_in[4];
    const float* bhh = (const float*)d_in[5];
    const float* lng = (const float*)d_in[6];
    const float* lnb = (const float*)d_in[7];
    const float* W1  = (const float*)d_in[8];
    const float* b1  = (const float*)d_in[9];
    const float* W2  = (const float*)d_in[10];
    const float* b2  = (const float*)d_in[11];
    const float* W3  = (const float*)d_in[12];
    const float* b3  = (const float*)d_in[13];

    float* out      = (float*)d_out;
    float* out_wl   = out;                      // 8192
    float* out_pad  = out + NB;                 // 39,321,600
    float* out_mask = out + NB + NB * 15 * 320; // 122,880

    // Stage gi (122880*96 floats = 11.8M) inside the padded_window region;
    // it is consumed by k2 before k3 overwrites it.
    float* gi = out_pad;

    dim3 g1(960, 3);
    k1_gi<<<g1, 128, 0, stream>>>(obs, act, Wih, bih, gi);
    k2_head<<<NB, 64, 0, stream>>>(obs, act, Whh, bhh, lng, lnb,
                                   W1, b1, W2, b2, W3, b3,
                                   gi, out_wl, out_mask);
    k3_window<<<38400, 256, 0, stream>>>(obs, act, out_mask, out_pad);
}

// Round 3
// 686.705 us; speedup vs baseline: 1.6733x; 1.0152x over previous
//
#include <hip/hip_runtime.h>
#include <math.h>

#define OBS 256
#define ACTD 64
#define NB 8192
#define NT 22
#define NSTEP 15

// ---------------------------------------------------------------------------
// Kernel 1: gi[b,t,j] = bias_ih[j] + sum_k x[b,t,k] * W_ih[j,k]
// Gate-split: blockIdx.y = gate block (32 rows of W_ih each).
// One thread per (b,t) row, 32 accumulators in VGPRs.
// __launch_bounds__(128, 4): cap 128 VGPRs so the allocator does NOT
// shuffle accumulators through AGPRs (R2: VGPR_Count=28 + 3x VALU issue).
// ---------------------------------------------------------------------------
__global__ __launch_bounds__(128, 4) void k1_gi(
    const float* __restrict__ obs, const float* __restrict__ act,
    const float* __restrict__ Wih, const float* __restrict__ bih,
    float* __restrict__ gi)
{
    int g = blockIdx.x * 128 + threadIdx.x;   // row id 0..122879
    int gate = blockIdx.y;                    // 0..2 (wave-uniform)
    int b = g / 15;
    int t = g - b * 15;
    const float* xo = obs + (size_t)(b * NT + t) * OBS;
    const float* xa = act + (size_t)(b * NT + t) * ACTD;
    const float* Wg = Wih + (size_t)gate * 32 * 320;
    const float* bg = bih + gate * 32;

    float acc[32];
#pragma unroll
    for (int j = 0; j < 32; ++j) acc[j] = bg[j];

    // obs part: k = 0..255
#pragma unroll 1
    for (int kb = 0; kb < 256; kb += 8) {
        float xv[8];
        float4 a0 = *(const float4*)(xo + kb + 0);
        float4 a1 = *(const float4*)(xo + kb + 4);
        xv[0]=a0.x; xv[1]=a0.y; xv[2]=a0.z; xv[3]=a0.w;
        xv[4]=a1.x; xv[5]=a1.y; xv[6]=a1.z; xv[7]=a1.w;
#pragma unroll
        for (int j = 0; j < 32; ++j) {
            const float* w = Wg + j * 320 + kb;
#pragma unroll
            for (int kk = 0; kk < 8; ++kk)
                acc[j] = fmaf(w[kk], xv[kk], acc[j]);
        }
    }
    // act part: k = 256..319
#pragma unroll 1
    for (int kb = 0; kb < 64; kb += 8) {
        float xv[8];
        float4 a0 = *(const float4*)(xa + kb + 0);
        float4 a1 = *(const float4*)(xa + kb + 4);
        xv[0]=a0.x; xv[1]=a0.y; xv[2]=a0.z; xv[3]=a0.w;
        xv[4]=a1.x; xv[5]=a1.y; xv[6]=a1.z; xv[7]=a1.w;
#pragma unroll
        for (int j = 0; j < 32; ++j) {
            const float* w = Wg + j * 320 + 256 + kb;
#pragma unroll
            for (int kk = 0; kk < 8; ++kk)
                acc[j] = fmaf(w[kk], xv[kk], acc[j]);
        }
    }

    float4* o = (float4*)(gi + (size_t)g * 96 + gate * 32);
#pragma unroll
    for (int j = 0; j < 8; ++j)
        o[j] = make_float4(acc[4*j], acc[4*j+1], acc[4*j+2], acc[4*j+3]);
}

// ---------------------------------------------------------------------------
// Kernel 2: per-row GRU recurrence + features + layernorm + MLP + argmax.
// One wave (64 threads) per batch row. Lanes mirror mod 32 for the gates.
// __launch_bounds__(64, 2): allow up to 256 real VGPRs (demand ~150) so the
// 96 weight regs + 32 hfull don't round-trip through AGPRs/scratch.
// ---------------------------------------------------------------------------
__global__ __launch_bounds__(64, 2) void k2_head(
    const float* __restrict__ obs, const float* __restrict__ act,
    const float* __restrict__ Whh, const float* __restrict__ bhh,
    const float* __restrict__ lng, const float* __restrict__ lnb,
    const float* __restrict__ W1, const float* __restrict__ b1,
    const float* __restrict__ W2, const float* __restrict__ b2,
    const float* __restrict__ W3, const float* __restrict__ b3,
    const float* __restrict__ gi,
    float* __restrict__ out_wl, float* __restrict__ out_mask)
{
    int b = blockIdx.x;
    int l = threadIdx.x;        // 0..63
    int jj = l & 31;            // gate row index (lanes 32..63 mirror 0..31)

    // preload W_hh rows jj, 32+jj, 64+jj and hidden biases
    float wr[32], wz[32], wn[32];
#pragma unroll
    for (int k = 0; k < 32; ++k) {
        wr[k] = Whh[(0  + jj) * 32 + k];
        wz[k] = Whh[(32 + jj) * 32 + k];
        wn[k] = Whh[(64 + jj) * 32 + k];
    }
    float br = bhh[jj], bz = bhh[32 + jj], bn = bhh[64 + jj];

    float hfull[32];
#pragma unroll
    for (int k = 0; k < 32; ++k) hfull[k] = 0.0f;
    float hown = 0.0f;

    const float* gib = gi + (size_t)b * NSTEP * 96;
    for (int t = 0; t < NSTEP; ++t) {
        float gi_r = gib[t * 96 + jj];
        float gi_z = gib[t * 96 + 32 + jj];
        float gi_n = gib[t * 96 + 64 + jj];
        float ar = br, az = bz, an = bn;
#pragma unroll
        for (int k = 0; k < 32; ++k) {
            ar = fmaf(wr[k], hfull[k], ar);
            az = fmaf(wz[k], hfull[k], az);
            an = fmaf(wn[k], hfull[k], an);
        }
        float r = 1.0f / (1.0f + expf(-(gi_r + ar)));
        float z = 1.0f / (1.0f + expf(-(gi_z + az)));
        float n = tanhf(gi_n + r * an);
        hown = (1.0f - z) * n + z * hown;
#pragma unroll
        for (int k = 0; k < 32; ++k) hfull[k] = __shfl(hown, k, 64);
    }
    // hfull now = h_n (identical on all 64 lanes)

    // ---- features ----
    float o14v[4], o13v[4], o12v[4], o11v[4];
#pragma unroll
    for (int q = 0; q < 4; ++q) {
        int i = l + 64 * q;
        o14v[q] = obs[(size_t)(b * NT + 14) * OBS + i];
        o13v[q] = obs[(size_t)(b * NT + 13) * OBS + i];
        o12v[q] = obs[(size_t)(b * NT + 12) * OBS + i];
        o11v[q] = obs[(size_t)(b * NT + 11) * OBS + i];
    }
    float ap = act[(size_t)(b * NT + 13) * ACTD + l];   // act_prev

    // softmax entropy over obs_t (row 14)
    float m = fmaxf(fmaxf(o14v[0], o14v[1]), fmaxf(o14v[2], o14v[3]));
#pragma unroll
    for (int o = 32; o >= 1; o >>= 1) m = fmaxf(m, __shfl_xor(m, o, 64));
    float e[4];
    float S = 0.0f, so = 0.0f;
#pragma unroll
    for (int q = 0; q < 4; ++q) {
        e[q] = expf(o14v[q] - m);
        S += e[q];
        so += o14v[q];
    }
#pragma unroll
    for (int o = 32; o >= 1; o >>= 1) { S += __shfl_xor(S, o, 64); so += __shfl_xor(so, o, 64); }
    float ent = 0.0f;
#pragma unroll
    for (int q = 0; q < 4; ++q) {
        float p = e[q] / S;
        ent += p * logf(p + 1e-8f);
    }
#pragma unroll
    for (int o = 32; o >= 1; o >>= 1) ent += __shfl_xor(ent, o, 64);
    ent = -ent;

    // rate of change
    float d1 = 0.0f, d2 = 0.0f, d3 = 0.0f;
#pragma unroll
    for (int q = 0; q < 4; ++q) {
        float a = o12v[q] - o11v[q]; d1 = fmaf(a, a, d1);
        a = o13v[q] - o12v[q];       d2 = fmaf(a, a, d2);
        a = o14v[q] - o13v[q];       d3 = fmaf(a, a, d3);
    }
#pragma unroll
    for (int o = 32; o >= 1; o >>= 1) {
        d1 += __shfl_xor(d1, o, 64); d2 += __shfl_xor(d2, o, 64); d3 += __shfl_xor(d3, o, 64);
    }
    float roc = (sqrtf(d1) + sqrtf(d2) + sqrtf(d3)) / 3.0f;

    // correlation
    float sa = ap;
#pragma unroll
    for (int o = 32; o >= 1; o >>= 1) sa += __shfl_xor(sa, o, 64);
    float mu_o = so / 256.0f;
    float mu_a = sa / 256.0f;
    float s_oa = 0.0f, s_oo = 0.0f, s_aa = 0.0f;
#pragma unroll
    for (int q = 0; q < 4; ++q) {
        float ov = o14v[q] - mu_o;
        float av = ((q == 0) ? ap : 0.0f) - mu_a;
        s_oa = fmaf(ov, av, s_oa);
        s_oo = fmaf(ov, ov, s_oo);
        s_aa = fmaf(av, av, s_aa);
    }
#pragma unroll
    for (int o = 32; o >= 1; o >>= 1) {
        s_oa += __shfl_xor(s_oa, o, 64); s_oo += __shfl_xor(s_oo, o, 64); s_aa += __shfl_xor(s_aa, o, 64);
    }
    float corr = s_oa / (sqrtf(s_oo) * sqrtf(s_aa) + 1e-8f);

    // ---- layernorm stats over feats[35] = [ent, roc, corr, h(32)] ----
    float fsum = ent + roc + corr;
#pragma unroll
    for (int k = 0; k < 32; ++k) fsum += hfull[k];
    float mu = fsum / 35.0f;
    float vs = (ent - mu) * (ent - mu) + (roc - mu) * (roc - mu) + (corr - mu) * (corr - mu);
#pragma unroll
    for (int k = 0; k < 32; ++k) { float dd = hfull[k] - mu; vs = fmaf(dd, dd, vs); }
    float inv_sv = 1.0f / sqrtf(vs / 35.0f + 1e-5f);

    // ---- MLP: layernorm fused into W1 dot, no scratch arrays ----
    float x1 = b1[l];
#pragma unroll
    for (int k = 0; k < 35; ++k) {
        float f = (k == 0) ? ent : (k == 1) ? roc : (k == 2) ? corr : hfull[k - 3];
        float fnk = (f - mu) * inv_sv * lng[k] + lnb[k];
        x1 = fmaf(W1[l * 35 + k], fnk, x1);
    }
    x1 = fmaxf(x1, 0.0f);

    float x2 = b2[jj];
#pragma unroll
    for (int k = 0; k < 64; ++k)
        x2 = fmaf(W2[jj * 64 + k], __shfl(x1, k, 64), x2);
    x2 = fmaxf(x2, 0.0f);

    int lr = (l < 14) ? l : 0;
    float lg = b3[lr];
#pragma unroll
    for (int k = 0; k < 32; ++k)
        lg = fmaf(W3[lr * 32 + k], __shfl(x2, k, 64), lg);

    // argmax over 14 logits (first max wins), redundantly on all lanes
    float best = -3.402823466e38f;
    int bi = 0;
#pragma unroll
    for (int j = 0; j < 14; ++j) {
        float v = __shfl(lg, j, 64);
        if (v > best) { best = v; bi = j; }
    }
    int wl = bi + 2;
    if (l == 0) out_wl[b] = (float)wl;
    int s  = (wl - 1) >> 1;
    int ee = wl >> 1;
    if (l < 15) {
        int off = l - 7;
        out_mask[b * 15 + l] = (off >= -s && off <= ee) ? 1.0f : 0.0f;
    }
}

// ---------------------------------------------------------------------------
// Kernel 3: padded_window = concat(obs[:,7:22], act[:,7:22]) * mask
// Pure bandwidth, float4 per thread. Exact grid: 8192*15*80 = 9,830,400.
// ---------------------------------------------------------------------------
__global__ __launch_bounds__(256) void k3_window(
    const float* __restrict__ obs, const float* __restrict__ act,
    const float* __restrict__ mask, float* __restrict__ out_pad)
{
    int idx = blockIdx.x * 256 + threadIdx.x;     // < 9830400
    int bt = idx / 80;
    int k4 = idx - bt * 80;
    int b = bt / 15;
    int t = bt - b * 15;
    float mval = mask[bt];
    float4 v;
    if (k4 < 64) {
        v = *(const float4*)(obs + (size_t)(b * NT + 7 + t) * OBS + k4 * 4);
    } else {
        v = *(const float4*)(act + (size_t)(b * NT + 7 + t) * ACTD + (k4 - 64) * 4);
    }
    v.x *= mval; v.y *= mval; v.z *= mval; v.w *= mval;
    ((float4*)out_pad)[idx] = v;
}

extern "C" void kernel_launch(void* const* d_in, const int* in_sizes, int n_in,
                              void* d_out, int out_size, void* d_ws, size_t ws_size,
                              hipStream_t stream) {
    const float* obs = (const float*)d_in[0];
    const float* act = (const float*)d_in[1];
    const float* Wih = (const float*)d_in[2];
    const float* Whh = (const float*)d_in[3];
    const float* bih = (const float*)d_in[4];
    const float* bhh = (const float*)d_in[5];
    const float* lng = (const float*)d_in[6];
    const float* lnb = (const float*)d_in[7];
    const float* W1  = (const float*)d_in[8];
    const float* b1  = (const float*)d_in[9];
    const float* W2  = (const float*)d_in[10];
    const float* b2  = (const float*)d_in[11];
    const float* W3  = (const float*)d_in[12];
    const float* b3  = (const float*)d_in[13];

    float* out      = (float*)d_out;
    float* out_wl   = out;                      // 8192
    float* out_pad  = out + NB;                 // 39,321,600
    float* out_mask = out + NB + NB * 15 * 320; // 122,880

    // Stage gi (122880*96 floats = 11.8M) inside the padded_window region;
    // it is consumed by k2 before k3 overwrites it.
    float* gi = out_pad;

    dim3 g1(960, 3);
    k1_gi<<<g1, 128, 0, stream>>>(obs, act, Wih, bih, gi);
    k2_head<<<NB, 64, 0, stream>>>(obs, act, Whh, bhh, lng, lnb,
                                   W1, b1, W2, b2, W3, b3,
                                   gi, out_wl, out_mask);
    k3_window<<<38400, 256, 0, stream>>>(obs, act, out_mask, out_pad);
}